// Round 9
// baseline (189.834 us; speedup 1.0000x reference)
//
#include <hip/hip_runtime.h>

#define IN_CH 128
#define OUT_CH 10
#define YPAD 16                    // y row padded to 64 B (one cache line)
#define SHIFT 10                   // nodes per bucket = 1024
#define NPB 1024
#define CHUNK_C 2048               // bincount chunk (small -> many blocks)
#define CHUNK_F 8192               // binfill chunk (long runs -> coalesced writes)
#define CCAP 1024                  // pairs per counting-sort round in k_accum
#define DSPL 8                     // deg slices per bucket (fixed)

// ============================================================================
// Shared helpers
// ============================================================================

// Detect whether edge_index arrived as int64 or int32 (odd words all zero
// for int64 values < 2^17). flag=1 -> int32, flag=0 -> int64. Deterministic.
__global__ void k_detect(const unsigned int* __restrict__ w, int* flag,
                         int nwords_check) {
    __shared__ int any_nz;
    if (threadIdx.x == 0) any_nz = 0;
    __syncthreads();
    int local = 0;
    for (int i = threadIdx.x; i < nwords_check; i += blockDim.x)
        if (w[2 * i + 1] != 0u) local = 1;
    if (local) atomicOr(&any_nz, 1);
    __syncthreads();
    if (threadIdx.x == 0) *flag = any_nz;
}

__global__ void k_zero_i(int* __restrict__ p, int n) {
    int i = blockIdx.x * blockDim.x + threadIdx.x;
    int stride = gridDim.x * blockDim.x;
    for (; i < n; i += stride) p[i] = 0;
}

__device__ __forceinline__ int load_dst(const void* ei, bool is32, long long E,
                                        long long i) {
    return is32 ? ((const int*)ei)[E + i] : (int)((const long long*)ei)[E + i];
}
__device__ __forceinline__ int load_src(const void* ei, bool is32, long long E,
                                        long long i) {
    return is32 ? ((const int*)ei)[i] : (int)((const long long*)ei)[i];
}

// ============================================================================
// Bucketed-gather path (primary)
// ============================================================================

// Per-chunk LDS histogram of buckets, flushed with one atomic per bucket.
__global__ void k_bincount(const void* __restrict__ ei,
                           const int* __restrict__ flag, int E,
                           int* __restrict__ bcnt, int NB) {
    __shared__ int h[1024];
    for (int i = threadIdx.x; i < NB; i += blockDim.x) h[i] = 0;
    __syncthreads();
    const bool is32 = (*flag != 0);
    long long base = (long long)blockIdx.x * CHUNK_C;
    int lim = (int)min((long long)CHUNK_C, (long long)E - base);
    for (int i = threadIdx.x; i < lim; i += blockDim.x) {
        int d = load_dst(ei, is32, E, base + i);
        atomicAdd(&h[d >> SHIFT], 1);
    }
    __syncthreads();
    for (int i = threadIdx.x; i < NB; i += blockDim.x)
        if (h[i]) atomicAdd(&bcnt[i], h[i]);
}

// Exclusive scan of bcnt[NB] (NB <= 1024) -> bbase, gcursor
__global__ void k_scanNB(const int* __restrict__ bcnt, int* __restrict__ bbase,
                         int* __restrict__ gcur, int NB) {
    __shared__ int s[1024];
    int tid = threadIdx.x;
    int v = (tid < NB) ? bcnt[tid] : 0;
    s[tid] = v;
    __syncthreads();
    for (int off = 1; off < 1024; off <<= 1) {
        int t = (tid >= off) ? s[tid - off] : 0;
        __syncthreads();
        s[tid] += t;
        __syncthreads();
    }
    if (tid < NB) {
        int e = s[tid] - v;
        bbase[tid] = e;
        gcur[tid] = e;
    }
}

// Per chunk: LDS hist -> reserve contiguous per-bucket runs via one global
// atomic per (block,bucket) -> write packed (src<<10 | dst&1023) into runs.
// With NB=98 buckets, runs are ~84 pairs = 336 B -> mostly full 32 B sectors,
// so the scattered stores write back at near line granularity.
__global__ void k_binfill(const void* __restrict__ ei,
                          const int* __restrict__ flag, int E,
                          int* __restrict__ gcur, int* __restrict__ pairs,
                          int NB) {
    __shared__ int h[1024];
    __shared__ int cur[1024];
    for (int i = threadIdx.x; i < NB; i += blockDim.x) h[i] = 0;
    __syncthreads();
    const bool is32 = (*flag != 0);
    long long base = (long long)blockIdx.x * CHUNK_F;
    int lim = (int)min((long long)CHUNK_F, (long long)E - base);
    for (int i = threadIdx.x; i < lim; i += blockDim.x) {
        int d = load_dst(ei, is32, E, base + i);
        atomicAdd(&h[d >> SHIFT], 1);
    }
    __syncthreads();
    for (int i = threadIdx.x; i < NB; i += blockDim.x)
        cur[i] = h[i] ? atomicAdd(&gcur[i], h[i]) : 0;
    __syncthreads();
    for (int i = threadIdx.x; i < lim; i += blockDim.x) {
        int s = load_src(ei, is32, E, base + i);
        int d = load_dst(ei, is32, E, base + i);
        int slot = atomicAdd(&cur[d >> SHIFT], 1);
        pairs[slot] = (int)(((unsigned)s << SHIFT) | (unsigned)(d & (NPB - 1)));
    }
}

// DSPL blocks per bucket: LDS histogram of the slice's dst rows, flushed
// NON-atomically to pdeg[blockIdx][1024] (coalesced). No global atomics.
__global__ void k_deg_part(const int* __restrict__ pairs,
                           const int* __restrict__ bbase,
                           const int* __restrict__ bcnt,
                           int* __restrict__ pdeg) {
    __shared__ int hist[NPB];
    int tid = threadIdx.x;
#pragma unroll
    for (int j = 0; j < NPB / 256; ++j) hist[tid + j * 256] = 0;
    __syncthreads();
    int b = blockIdx.x >> 3;
    int s = blockIdx.x & 7;
    int beg = bbase[b], c = bcnt[b];
    int lo = beg + (int)(((long long)c * s) >> 3);
    int hi = beg + (int)(((long long)c * (s + 1)) >> 3);
    for (int i = lo + tid; i < hi; i += 256)
        atomicAdd(&hist[((unsigned)pairs[i]) & (NPB - 1)], 1);
    __syncthreads();
    int* dst = pdeg + (size_t)blockIdx.x * NPB;
#pragma unroll
    for (int j = 0; j < NPB / 256; ++j)
        dst[tid + j * 256] = hist[tid + j * 256];
}

// Per node: deg = sum of DSPL partials; dinv = rsqrt(1+deg);
// y[n] = dinv * (x[n] @ W), row padded to YPAD floats (64 B aligned).
__global__ void k_xw(const float* __restrict__ x, const float* __restrict__ W,
                     const int* __restrict__ pdeg, float* __restrict__ dinv,
                     float* __restrict__ y, int N) {
    __shared__ float Wt[OUT_CH][IN_CH];
    for (int i = threadIdx.x; i < IN_CH * OUT_CH; i += blockDim.x) {
        int k = i / OUT_CH, c = i - k * OUT_CH;
        Wt[c][k] = W[i];
    }
    __syncthreads();

    int n = blockIdx.x * blockDim.x + threadIdx.x;
    if (n >= N) return;

    float acc[OUT_CH];
#pragma unroll
    for (int c = 0; c < OUT_CH; ++c) acc[c] = 0.0f;

    const float4* xr = (const float4*)(x + (size_t)n * IN_CH);
#pragma unroll 4
    for (int k4 = 0; k4 < IN_CH / 4; ++k4) {
        float4 xv = xr[k4];
#pragma unroll
        for (int c = 0; c < OUT_CH; ++c) {
            float4 wv = *(const float4*)&Wt[c][k4 * 4];
            acc[c] += xv.x * wv.x + xv.y * wv.y + xv.z * wv.z + xv.w * wv.w;
        }
    }

    int b = n >> SHIFT, l = n & (NPB - 1);
    const int* pd = pdeg + ((size_t)b * DSPL) * NPB + l;
    int deg = 0;
#pragma unroll
    for (int s = 0; s < DSPL; ++s) deg += pd[(size_t)s * NPB];
    float d = rsqrtf(1.0f + (float)deg);
    dinv[n] = d;

    float4* yr = (float4*)(y + (size_t)n * YPAD);
    float4 o0, o1;
    o0.x = d * acc[0]; o0.y = d * acc[1]; o0.z = d * acc[2]; o0.w = d * acc[3];
    o1.x = d * acc[4]; o1.y = d * acc[5]; o1.z = d * acc[6]; o1.w = d * acc[7];
    yr[0] = o0;
    yr[1] = o1;
    float2 o2;
    o2.x = d * acc[8]; o2.y = d * acc[9];
    ((float2*)yr)[4] = o2;
}

// SPLIT blocks per bucket, block (b,s) owns slice s of bucket b's pairs.
// Per <=1024-pair round: counting-sort by the 1024 dst rows in LDS (native
// int atomics), then each thread privately accumulates its 4 rows' runs of
// y[src] gathers in VGPRs (acc[4][10]). Partial flushed coalesced (each
// thread writes 160 contiguous bytes). ZERO float atomics anywhere.
__global__ void k_accum(const int* __restrict__ pairs,
                        const int* __restrict__ bbase,
                        const int* __restrict__ bcnt,
                        const float* __restrict__ y, float* __restrict__ part,
                        int split_log) {
    __shared__ int hist[NPB];
    __shared__ int base[NPB];
    __shared__ int cur[NPB];
    __shared__ unsigned sorted[CCAP];
    __shared__ int tsum[256];

    int tid = threadIdx.x;
    int b = blockIdx.x >> split_log;
    int s = blockIdx.x & ((1 << split_log) - 1);
    int beg = bbase[b];
    int c = bcnt[b];
    int lo = beg + (int)(((long long)c * s) >> split_log);
    int hi = beg + (int)(((long long)c * (s + 1)) >> split_log);

    int r0 = tid * 4;  // this thread owns rows r0..r0+3

    float acc[4][OUT_CH];
#pragma unroll
    for (int j = 0; j < 4; ++j)
#pragma unroll
        for (int k = 0; k < OUT_CH; ++k) acc[j][k] = 0.0f;

    for (int clo = lo; clo < hi; clo += CCAP) {
        int m = min(CCAP, hi - clo);

#pragma unroll
        for (int j = 0; j < 4; ++j) hist[r0 + j] = 0;
        __syncthreads();

        // read my <=4 pairs, build row histogram (native int LDS atomics)
        unsigned mine[4];
        int nm = 0;
        for (int i = tid; i < m; i += 256) {
            unsigned pp = (unsigned)pairs[clo + i];
            mine[nm++] = pp;
            atomicAdd(&hist[pp & (NPB - 1)], 1);
        }
        __syncthreads();

        // block-wide exclusive scan over 1024 rows (4 per thread)
        int lsum = hist[r0] + hist[r0 + 1] + hist[r0 + 2] + hist[r0 + 3];
        tsum[tid] = lsum;
        __syncthreads();
        for (int off = 1; off < 256; off <<= 1) {
            int t = (tid >= off) ? tsum[tid - off] : 0;
            __syncthreads();
            tsum[tid] += t;
            __syncthreads();
        }
        int run = tsum[tid] - lsum;
#pragma unroll
        for (int j = 0; j < 4; ++j) {
            base[r0 + j] = run;
            cur[r0 + j] = run;
            run += hist[r0 + j];
        }
        __syncthreads();

        // scatter src ids into row-sorted LDS order
        for (int j = 0; j < nm; ++j) {
            unsigned pp = mine[j];
            int slot = atomicAdd(&cur[pp & (NPB - 1)], 1);
            sorted[slot] = pp >> SHIFT;
        }
        __syncthreads();

        // private VGPR accumulation over my 4 rows' contiguous runs
#pragma unroll
        for (int j = 0; j < 4; ++j) {
            int rb = base[r0 + j];
            int rl = hist[r0 + j];
            for (int q = 0; q < rl; ++q) {
                unsigned src = sorted[rb + q];
                const float4* yr = (const float4*)(y + (size_t)src * YPAD);
                float4 v0 = yr[0];
                float4 v1 = yr[1];
                float2 v2 = ((const float2*)yr)[4];
                acc[j][0] += v0.x; acc[j][1] += v0.y;
                acc[j][2] += v0.z; acc[j][3] += v0.w;
                acc[j][4] += v1.x; acc[j][5] += v1.y;
                acc[j][6] += v1.z; acc[j][7] += v1.w;
                acc[j][8] += v2.x; acc[j][9] += v2.y;
            }
        }
        __syncthreads();  // protect hist/sorted before next round
    }

    // flush partial: thread writes 160 contiguous bytes (rows r0..r0+3)
    float* dst = part + (size_t)blockIdx.x * (NPB * OUT_CH) +
                 (size_t)r0 * OUT_CH;
#pragma unroll
    for (int j = 0; j < 4; ++j)
#pragma unroll
        for (int k = 0; k < OUT_CH; ++k) dst[j * OUT_CH + k] = acc[j][k];
}

// out[n][ch] = dinv[n] * (sum of SPLIT partials + y[n][ch]) + bias[ch]
__global__ void k_merge(const float* __restrict__ part,
                        const float* __restrict__ y,
                        const float* __restrict__ dinv,
                        const float* __restrict__ bias,
                        float* __restrict__ out, int N, int split_log) {
    int idx = blockIdx.x * blockDim.x + threadIdx.x;
    if (idx >= N * OUT_CH) return;
    int n = idx / OUT_CH;
    int ch = idx - n * OUT_CH;
    int b = n >> SHIFT;
    int local = (n & (NPB - 1)) * OUT_CH + ch;
    int spl = 1 << split_log;
    size_t bs = (size_t)b << split_log;
    float s = 0.0f;
    for (int q = 0; q < spl; ++q)
        s += part[(bs + q) * (size_t)(NPB * OUT_CH) + local];
    out[idx] = dinv[n] * (s + y[(size_t)n * YPAD + ch]) + bias[ch];
}

// ============================================================================
// Fallback path (atomic scatter) — used only if ws too small / N too large
// ============================================================================

__global__ void k_count_fb(const void* __restrict__ ei, int* __restrict__ cnt,
                           const int* __restrict__ flag, int E) {
    const bool is32 = (*flag != 0);
    long long i = (long long)blockIdx.x * blockDim.x + threadIdx.x;
    long long stride = (long long)gridDim.x * blockDim.x;
    for (; i < E; i += stride) atomicAdd(&cnt[load_dst(ei, is32, E, i)], 1);
}

__global__ void k_xw_fb(const float* __restrict__ x,
                        const float* __restrict__ W,
                        const int* __restrict__ cnt, float* __restrict__ dinv,
                        float* __restrict__ y, float* __restrict__ out_seed,
                        int N) {
    __shared__ float Wt[OUT_CH][IN_CH];
    for (int i = threadIdx.x; i < IN_CH * OUT_CH; i += blockDim.x) {
        int k = i / OUT_CH, c = i - k * OUT_CH;
        Wt[c][k] = W[i];
    }
    __syncthreads();
    int n = blockIdx.x * blockDim.x + threadIdx.x;
    if (n >= N) return;
    float acc[OUT_CH];
#pragma unroll
    for (int c = 0; c < OUT_CH; ++c) acc[c] = 0.0f;
    const float4* xr = (const float4*)(x + (size_t)n * IN_CH);
#pragma unroll 4
    for (int k4 = 0; k4 < IN_CH / 4; ++k4) {
        float4 xv = xr[k4];
#pragma unroll
        for (int c = 0; c < OUT_CH; ++c) {
            float4 wv = *(const float4*)&Wt[c][k4 * 4];
            acc[c] += xv.x * wv.x + xv.y * wv.y + xv.z * wv.z + xv.w * wv.w;
        }
    }
    float d = rsqrtf(1.0f + (float)cnt[n]);
    dinv[n] = d;
    float2* yr = (float2*)(y + (size_t)n * OUT_CH);
    float2* orow = (float2*)(out_seed + (size_t)n * OUT_CH);
#pragma unroll
    for (int c2 = 0; c2 < OUT_CH / 2; ++c2) {
        float2 v;
        v.x = d * acc[2 * c2];
        v.y = d * acc[2 * c2 + 1];
        yr[c2] = v;
        orow[c2] = v;
    }
}

__global__ void k_scatter_fb(const void* __restrict__ ei,
                             const float* __restrict__ y,
                             float* __restrict__ out,
                             const int* __restrict__ flag, int E) {
    const bool is32 = (*flag != 0);
    long long i = (long long)blockIdx.x * blockDim.x + threadIdx.x;
    long long stride = (long long)gridDim.x * blockDim.x;
    for (; i < E; i += stride) {
        long long s = load_src(ei, is32, E, i);
        long long t = load_dst(ei, is32, E, i);
        const float2* yr = (const float2*)(y + s * OUT_CH);
        float2 v0 = yr[0], v1 = yr[1], v2 = yr[2], v3 = yr[3], v4 = yr[4];
        float* orow = out + t * OUT_CH;
        atomicAdd(&orow[0], v0.x);
        atomicAdd(&orow[1], v0.y);
        atomicAdd(&orow[2], v1.x);
        atomicAdd(&orow[3], v1.y);
        atomicAdd(&orow[4], v2.x);
        atomicAdd(&orow[5], v2.y);
        atomicAdd(&orow[6], v3.x);
        atomicAdd(&orow[7], v3.y);
        atomicAdd(&orow[8], v4.x);
        atomicAdd(&orow[9], v4.y);
    }
}

__global__ void k_final_fb(const float* __restrict__ dinv,
                           const float* __restrict__ b,
                           float* __restrict__ out, int N) {
    int n = blockIdx.x * blockDim.x + threadIdx.x;
    if (n >= N) return;
    float d = dinv[n];
    float2* orow = (float2*)(out + (size_t)n * OUT_CH);
#pragma unroll
    for (int c2 = 0; c2 < OUT_CH / 2; ++c2) {
        float2 v = orow[c2];
        v.x = v.x * d + b[2 * c2];
        v.y = v.y * d + b[2 * c2 + 1];
        orow[c2] = v;
    }
}

// ============================================================================
// Launch
// ============================================================================

extern "C" void kernel_launch(void* const* d_in, const int* in_sizes, int n_in,
                              void* d_out, int out_size, void* d_ws,
                              size_t ws_size, hipStream_t stream) {
    const float* x = (const float*)d_in[0];
    const void* ei = d_in[1];
    const float* W = (const float*)d_in[2];
    const float* b = (const float*)d_in[3];
    float* out = (float*)d_out;

    int N = in_sizes[0] / IN_CH;  // 100000
    int E = in_sizes[1] / 2;      // 3200000

    int NB = (N + NPB - 1) >> SHIFT;  // buckets (98)
    int nblkN = (N + 255) / 256;
    int nblkC = (E + CHUNK_C - 1) / CHUNK_C;
    int nblkF = (E + CHUNK_F - 1) / CHUNK_F;

    // primary ws layout (4B units):
    //   bcnt[NB] | bbase[NB] | gcur[NB] | flag | pad16 | pdeg[NB*8*1024] |
    //   dinv[N] | pad16 | y[16N] | pairs[E] | pad16 | part[NB*SPL*10240]
    size_t off_pdeg = (((size_t)3 * NB + 1) + 15) & ~(size_t)15;
    size_t off_dinv = off_pdeg + (size_t)NB * DSPL * NPB;
    size_t off_y = ((off_dinv + (size_t)N) + 15) & ~(size_t)15;
    size_t off_pairs = off_y + (size_t)YPAD * N;
    size_t off_part = ((off_pairs + (size_t)E) + 15) & ~(size_t)15;

    // adaptive split: largest of {8,4,2,1} whose partial buffer fits in ws
    int split_log = -1;
    for (int sl = 3; sl >= 0; --sl) {
        size_t needed =
            (off_part + ((size_t)NB << sl) * (NPB * OUT_CH)) * 4;
        if (ws_size >= needed) {
            split_log = sl;
            break;
        }
    }

    if (split_log >= 0 && NB <= 1024 && N <= (1 << 22)) {
        int* wsi = (int*)d_ws;
        int* bcnt = wsi;
        int* bbase = bcnt + NB;
        int* gcur = bbase + NB;
        int* flag = gcur + NB;
        int* pdeg = wsi + off_pdeg;
        float* dinv = (float*)(wsi + off_dinv);
        float* y = (float*)(wsi + off_y);
        int* pairs = wsi + off_pairs;
        float* part = (float*)(wsi + off_part);

        k_zero_i<<<1, 256, 0, stream>>>(bcnt, NB);
        k_detect<<<1, 256, 0, stream>>>((const unsigned int*)ei, flag, 8192);
        k_bincount<<<nblkC, 256, 0, stream>>>(ei, flag, E, bcnt, NB);
        k_scanNB<<<1, 1024, 0, stream>>>(bcnt, bbase, gcur, NB);
        k_binfill<<<nblkF, 256, 0, stream>>>(ei, flag, E, gcur, pairs, NB);
        k_deg_part<<<NB * DSPL, 256, 0, stream>>>(pairs, bbase, bcnt, pdeg);
        k_xw<<<nblkN, 256, 0, stream>>>(x, W, pdeg, dinv, y, N);
        k_accum<<<NB << split_log, 256, 0, stream>>>(pairs, bbase, bcnt, y,
                                                     part, split_log);
        int mthreads = N * OUT_CH;
        k_merge<<<(mthreads + 255) / 256, 256, 0, stream>>>(part, y, dinv, b,
                                                            out, N, split_log);
    } else {
        // -------- fallback: atomic scatter --------
        int* wsi = (int*)d_ws;
        int* cnt = wsi;                     // N
        int* flag = cnt + N;                // 1
        size_t off = ((size_t)N + 2) & ~(size_t)1;
        float* dinv = (float*)(wsi + off);  // N
        float* y = dinv + N;                // 10N

        k_zero_i<<<nblkN, 256, 0, stream>>>(cnt, N);
        k_detect<<<1, 256, 0, stream>>>((const unsigned int*)ei, flag, 8192);
        k_count_fb<<<4096, 256, 0, stream>>>(ei, cnt, flag, E);
        k_xw_fb<<<nblkN, 256, 0, stream>>>(x, W, cnt, dinv, y, out, N);
        k_scatter_fb<<<4096, 256, 0, stream>>>(ei, y, out, flag, E);
        k_final_fb<<<nblkN, 256, 0, stream>>>(dinv, b, out, N);
    }
}

// Round 10
// 153.558 us; speedup vs baseline: 1.2362x; 1.2362x over previous
//
#include <hip/hip_runtime.h>

#define IN_CH 128
#define OUT_CH 10
#define SHIFT 10                   // nodes per bucket = 1024
#define NPB 1024
#define CHUNK_C 2048               // bincount chunk
#define CHUNK_F 4096               // binfill chunk (runs ~42 pairs = 168 B)
#define CCAP 2048                  // pairs per counting-sort round in k_accum
#define DSPL 8                     // deg slices per bucket

// bf16 helpers (RNE pack, shift unpack)
__device__ __forceinline__ unsigned pk2(float a, float b) {
    unsigned ua = __float_as_uint(a);
    ua = (ua + 0x7fffu + ((ua >> 16) & 1u)) >> 16;
    unsigned ub = __float_as_uint(b);
    ub = (ub + 0x7fffu + ((ub >> 16) & 1u)) >> 16;
    return ua | (ub << 16);
}
__device__ __forceinline__ float lo16(unsigned u) {
    return __uint_as_float(u << 16);
}
__device__ __forceinline__ float hi16(unsigned u) {
    return __uint_as_float(u & 0xffff0000u);
}

// ============================================================================
// Shared helpers
// ============================================================================

__device__ __forceinline__ int load_dst(const void* ei, bool is32, long long E,
                                        long long i) {
    return is32 ? ((const int*)ei)[E + i] : (int)((const long long*)ei)[E + i];
}
__device__ __forceinline__ int load_src(const void* ei, bool is32, long long E,
                                        long long i) {
    return is32 ? ((const int*)ei)[i] : (int)((const long long*)ei)[i];
}

// Fused: zero bcnt + int64/int32 detect (odd 32-bit words all zero -> int64).
__global__ void k_init(const unsigned int* __restrict__ w,
                       int* __restrict__ bcnt, int* __restrict__ flag, int NB,
                       int nwords_check) {
    __shared__ int any_nz;
    for (int i = threadIdx.x; i < NB; i += 256) bcnt[i] = 0;
    if (threadIdx.x == 0) any_nz = 0;
    __syncthreads();
    int local = 0;
    for (int i = threadIdx.x; i < nwords_check; i += 256)
        if (w[2 * i + 1] != 0u) local = 1;
    if (local) atomicOr(&any_nz, 1);
    __syncthreads();
    if (threadIdx.x == 0) *flag = any_nz;
}

__global__ void k_zero_i(int* __restrict__ p, int n) {
    int i = blockIdx.x * blockDim.x + threadIdx.x;
    int stride = gridDim.x * blockDim.x;
    for (; i < n; i += stride) p[i] = 0;
}

// ============================================================================
// Bucketed-gather path (primary)
// ============================================================================

// Per-chunk LDS histogram of buckets, one global atomic per bucket.
__global__ void k_bincount(const void* __restrict__ ei,
                           const int* __restrict__ flag, int E,
                           int* __restrict__ bcnt, int NB) {
    __shared__ int h[128];
    for (int i = threadIdx.x; i < NB; i += blockDim.x) h[i] = 0;
    __syncthreads();
    const bool is32 = (*flag != 0);
    long long base = (long long)blockIdx.x * CHUNK_C;
    int lim = (int)min((long long)CHUNK_C, (long long)E - base);
    for (int i = threadIdx.x; i < lim; i += blockDim.x) {
        int d = load_dst(ei, is32, E, base + i);
        atomicAdd(&h[d >> SHIFT], 1);
    }
    __syncthreads();
    for (int i = threadIdx.x; i < NB; i += blockDim.x)
        if (h[i]) atomicAdd(&bcnt[i], h[i]);
}

// Exclusive scan of bcnt[NB] (NB <= 128) -> bbase, gcursor
__global__ void k_scanNB(const int* __restrict__ bcnt, int* __restrict__ bbase,
                         int* __restrict__ gcur, int NB) {
    __shared__ int s[128];
    int tid = threadIdx.x;
    int v = (tid < NB) ? bcnt[tid] : 0;
    if (tid < 128) s[tid] = v;
    __syncthreads();
    for (int off = 1; off < 128; off <<= 1) {
        int t = (tid < 128 && tid >= off) ? s[tid - off] : 0;
        __syncthreads();
        if (tid < 128) s[tid] += t;
        __syncthreads();
    }
    if (tid < NB) {
        int e = s[tid] - v;
        bbase[tid] = e;
        gcur[tid] = e;
    }
}

// Per chunk: LDS hist -> reserve per-bucket runs (1 global atomic each) ->
// write packed (src<<10 | dst&1023). Runs ~42 pairs = 168 B -> full sectors.
__global__ void k_binfill(const void* __restrict__ ei,
                          const int* __restrict__ flag, int E,
                          int* __restrict__ gcur, int* __restrict__ pairs,
                          int NB) {
    __shared__ int h[128];
    __shared__ int cur[128];
    for (int i = threadIdx.x; i < NB; i += blockDim.x) h[i] = 0;
    __syncthreads();
    const bool is32 = (*flag != 0);
    long long base = (long long)blockIdx.x * CHUNK_F;
    int lim = (int)min((long long)CHUNK_F, (long long)E - base);
    for (int i = threadIdx.x; i < lim; i += blockDim.x) {
        int d = load_dst(ei, is32, E, base + i);
        atomicAdd(&h[d >> SHIFT], 1);
    }
    __syncthreads();
    for (int i = threadIdx.x; i < NB; i += blockDim.x)
        cur[i] = h[i] ? atomicAdd(&gcur[i], h[i]) : 0;
    __syncthreads();
    for (int i = threadIdx.x; i < lim; i += blockDim.x) {
        int s = load_src(ei, is32, E, base + i);
        int d = load_dst(ei, is32, E, base + i);
        int slot = atomicAdd(&cur[d >> SHIFT], 1);
        pairs[slot] = (int)(((unsigned)s << SHIFT) | (unsigned)(d & (NPB - 1)));
    }
}

// DSPL blocks per bucket: LDS histogram of the slice's dst rows, flushed
// NON-atomically to pdeg[blockIdx][1024] (coalesced). No global atomics.
__global__ void k_deg_part(const int* __restrict__ pairs,
                           const int* __restrict__ bbase,
                           const int* __restrict__ bcnt,
                           int* __restrict__ pdeg) {
    __shared__ int hist[NPB];
    int tid = threadIdx.x;
#pragma unroll
    for (int j = 0; j < NPB / 256; ++j) hist[tid + j * 256] = 0;
    __syncthreads();
    int b = blockIdx.x >> 3;
    int s = blockIdx.x & 7;
    int beg = bbase[b], c = bcnt[b];
    int lo = beg + (int)(((long long)c * s) >> 3);
    int hi = beg + (int)(((long long)c * (s + 1)) >> 3);
    for (int i = lo + tid; i < hi; i += 256)
        atomicAdd(&hist[((unsigned)pairs[i]) & (NPB - 1)], 1);
    __syncthreads();
    int* dst = pdeg + (size_t)blockIdx.x * NPB;
#pragma unroll
    for (int j = 0; j < NPB / 256; ++j)
        dst[tid + j * 256] = hist[tid + j * 256];
}

// Per node: deg = sum of DSPL partials; dinv = rsqrt(1+deg);
// y[n] = dinv * (x[n] @ W) packed bf16x2 into 5 u32 words of an 8-word
// (32 B, one half cache line) row.
__global__ void k_xw(const float* __restrict__ x, const float* __restrict__ W,
                     const int* __restrict__ pdeg, float* __restrict__ dinv,
                     unsigned* __restrict__ yw, int N) {
    __shared__ float Wt[OUT_CH][IN_CH];
    for (int i = threadIdx.x; i < IN_CH * OUT_CH; i += blockDim.x) {
        int k = i / OUT_CH, c = i - k * OUT_CH;
        Wt[c][k] = W[i];
    }
    __syncthreads();

    int n = blockIdx.x * blockDim.x + threadIdx.x;
    if (n >= N) return;

    float acc[OUT_CH];
#pragma unroll
    for (int c = 0; c < OUT_CH; ++c) acc[c] = 0.0f;

    const float4* xr = (const float4*)(x + (size_t)n * IN_CH);
#pragma unroll 4
    for (int k4 = 0; k4 < IN_CH / 4; ++k4) {
        float4 xv = xr[k4];
#pragma unroll
        for (int c = 0; c < OUT_CH; ++c) {
            float4 wv = *(const float4*)&Wt[c][k4 * 4];
            acc[c] += xv.x * wv.x + xv.y * wv.y + xv.z * wv.z + xv.w * wv.w;
        }
    }

    int b = n >> SHIFT, l = n & (NPB - 1);
    const int* pd = pdeg + ((size_t)b * DSPL) * NPB + l;
    int deg = 0;
#pragma unroll
    for (int s = 0; s < DSPL; ++s) deg += pd[(size_t)s * NPB];
    float d = rsqrtf(1.0f + (float)deg);
    dinv[n] = d;

    uint4 w0;
    w0.x = pk2(d * acc[0], d * acc[1]);
    w0.y = pk2(d * acc[2], d * acc[3]);
    w0.z = pk2(d * acc[4], d * acc[5]);
    w0.w = pk2(d * acc[6], d * acc[7]);
    *(uint4*)(yw + (size_t)n * 8) = w0;
    yw[(size_t)n * 8 + 4] = pk2(d * acc[8], d * acc[9]);
}

// SPLIT blocks per bucket, 512 threads. Per <=2048-pair round: counting-sort
// by the 1024 dst rows in LDS (native int atomics; shfl wave-scan for the
// prefix), then each thread privately accumulates its 2 rows' runs of
// bf16 y[src] gathers in VGPRs. Partials flushed coalesced. No float atomics.
__global__ void k_accum(const int* __restrict__ pairs,
                        const int* __restrict__ bbase,
                        const int* __restrict__ bcnt,
                        const unsigned* __restrict__ yw,
                        float* __restrict__ part, int split_log) {
    __shared__ int hist[NPB];
    __shared__ int base[NPB];
    __shared__ int cur[NPB];
    __shared__ unsigned sorted[CCAP];
    __shared__ int wsums[8];

    int tid = threadIdx.x;
    int lane = tid & 63;
    int wid = tid >> 6;
    int b = blockIdx.x >> split_log;
    int s = blockIdx.x & ((1 << split_log) - 1);
    int beg = bbase[b];
    int c = bcnt[b];
    int lo = beg + (int)(((long long)c * s) >> split_log);
    int hi = beg + (int)(((long long)c * (s + 1)) >> split_log);

    int r0 = tid * 2;  // this thread owns rows r0, r0+1

    float acc[2][OUT_CH];
#pragma unroll
    for (int j = 0; j < 2; ++j)
#pragma unroll
        for (int k = 0; k < OUT_CH; ++k) acc[j][k] = 0.0f;

    for (int clo = lo; clo < hi; clo += CCAP) {
        int m = min(CCAP, hi - clo);

        hist[r0] = 0;
        hist[r0 + 1] = 0;
        __syncthreads();

        // read my <=4 pairs, build row histogram (native int LDS atomics)
        unsigned mine[4];
        int nm = 0;
        for (int i = tid; i < m; i += 512) {
            unsigned pp = (unsigned)pairs[clo + i];
            mine[nm++] = pp;
            atomicAdd(&hist[pp & (NPB - 1)], 1);
        }
        __syncthreads();

        // exclusive scan over 1024 rows: shfl wave-scan + cross-wave fixup
        int lsum = hist[r0] + hist[r0 + 1];
        int incl = lsum;
#pragma unroll
        for (int off = 1; off < 64; off <<= 1) {
            int t = __shfl_up(incl, off);
            if (lane >= off) incl += t;
        }
        if (lane == 63) wsums[wid] = incl;
        __syncthreads();
        int run = incl - lsum;
        for (int w = 0; w < wid; ++w) run += wsums[w];
        base[r0] = run;
        cur[r0] = run;
        run += hist[r0];
        base[r0 + 1] = run;
        cur[r0 + 1] = run;
        __syncthreads();

        // scatter src ids into row-sorted LDS order
        for (int j = 0; j < nm; ++j) {
            unsigned pp = mine[j];
            int slot = atomicAdd(&cur[pp & (NPB - 1)], 1);
            sorted[slot] = pp >> SHIFT;
        }
        __syncthreads();

        // private VGPR accumulation over my 2 rows' contiguous runs
#pragma unroll
        for (int j = 0; j < 2; ++j) {
            int rb = base[r0 + j];
            int rl = hist[r0 + j];
            for (int q = 0; q < rl; ++q) {
                unsigned src = sorted[rb + q];
                const unsigned* yr = yw + (size_t)src * 8;
                uint4 a = *(const uint4*)yr;
                unsigned w4 = yr[4];
                acc[j][0] += lo16(a.x); acc[j][1] += hi16(a.x);
                acc[j][2] += lo16(a.y); acc[j][3] += hi16(a.y);
                acc[j][4] += lo16(a.z); acc[j][5] += hi16(a.z);
                acc[j][6] += lo16(a.w); acc[j][7] += hi16(a.w);
                acc[j][8] += lo16(w4);  acc[j][9] += hi16(w4);
            }
        }
        __syncthreads();  // protect hist/sorted/wsums before next round
    }

    // flush partial: thread writes 80 contiguous bytes (rows r0, r0+1)
    float* dst = part + (size_t)blockIdx.x * (NPB * OUT_CH) +
                 (size_t)r0 * OUT_CH;
#pragma unroll
    for (int j = 0; j < 2; ++j)
#pragma unroll
        for (int k = 0; k < OUT_CH; ++k) dst[j * OUT_CH + k] = acc[j][k];
}

// out[n][ch] = dinv[n] * (sum of SPLIT partials + y[n][ch]) + bias[ch]
__global__ void k_merge(const float* __restrict__ part,
                        const unsigned* __restrict__ yw,
                        const float* __restrict__ dinv,
                        const float* __restrict__ bias,
                        float* __restrict__ out, int N, int split_log) {
    int idx = blockIdx.x * blockDim.x + threadIdx.x;
    if (idx >= N * OUT_CH) return;
    int n = idx / OUT_CH;
    int ch = idx - n * OUT_CH;
    int b = n >> SHIFT;
    int local = (n & (NPB - 1)) * OUT_CH + ch;
    int spl = 1 << split_log;
    size_t bs = (size_t)b << split_log;
    float s = 0.0f;
    for (int q = 0; q < spl; ++q)
        s += part[(bs + q) * (size_t)(NPB * OUT_CH) + local];
    unsigned w = yw[(size_t)n * 8 + (ch >> 1)];
    float yv = (ch & 1) ? hi16(w) : lo16(w);
    out[idx] = dinv[n] * (s + yv) + bias[ch];
}

// ============================================================================
// Fallback path (atomic scatter) — used only if ws too small / N too large
// ============================================================================

__global__ void k_detect_fb(const unsigned int* __restrict__ w, int* flag,
                            int nwords_check) {
    __shared__ int any_nz;
    if (threadIdx.x == 0) any_nz = 0;
    __syncthreads();
    int local = 0;
    for (int i = threadIdx.x; i < nwords_check; i += blockDim.x)
        if (w[2 * i + 1] != 0u) local = 1;
    if (local) atomicOr(&any_nz, 1);
    __syncthreads();
    if (threadIdx.x == 0) *flag = any_nz;
}

__global__ void k_count_fb(const void* __restrict__ ei, int* __restrict__ cnt,
                           const int* __restrict__ flag, int E) {
    const bool is32 = (*flag != 0);
    long long i = (long long)blockIdx.x * blockDim.x + threadIdx.x;
    long long stride = (long long)gridDim.x * blockDim.x;
    for (; i < E; i += stride) atomicAdd(&cnt[load_dst(ei, is32, E, i)], 1);
}

__global__ void k_xw_fb(const float* __restrict__ x,
                        const float* __restrict__ W,
                        const int* __restrict__ cnt, float* __restrict__ dinv,
                        float* __restrict__ y, float* __restrict__ out_seed,
                        int N) {
    __shared__ float Wt[OUT_CH][IN_CH];
    for (int i = threadIdx.x; i < IN_CH * OUT_CH; i += blockDim.x) {
        int k = i / OUT_CH, c = i - k * OUT_CH;
        Wt[c][k] = W[i];
    }
    __syncthreads();
    int n = blockIdx.x * blockDim.x + threadIdx.x;
    if (n >= N) return;
    float acc[OUT_CH];
#pragma unroll
    for (int c = 0; c < OUT_CH; ++c) acc[c] = 0.0f;
    const float4* xr = (const float4*)(x + (size_t)n * IN_CH);
#pragma unroll 4
    for (int k4 = 0; k4 < IN_CH / 4; ++k4) {
        float4 xv = xr[k4];
#pragma unroll
        for (int c = 0; c < OUT_CH; ++c) {
            float4 wv = *(const float4*)&Wt[c][k4 * 4];
            acc[c] += xv.x * wv.x + xv.y * wv.y + xv.z * wv.z + xv.w * wv.w;
        }
    }
    float d = rsqrtf(1.0f + (float)cnt[n]);
    dinv[n] = d;
    float2* yr = (float2*)(y + (size_t)n * OUT_CH);
    float2* orow = (float2*)(out_seed + (size_t)n * OUT_CH);
#pragma unroll
    for (int c2 = 0; c2 < OUT_CH / 2; ++c2) {
        float2 v;
        v.x = d * acc[2 * c2];
        v.y = d * acc[2 * c2 + 1];
        yr[c2] = v;
        orow[c2] = v;
    }
}

__global__ void k_scatter_fb(const void* __restrict__ ei,
                             const float* __restrict__ y,
                             float* __restrict__ out,
                             const int* __restrict__ flag, int E) {
    const bool is32 = (*flag != 0);
    long long i = (long long)blockIdx.x * blockDim.x + threadIdx.x;
    long long stride = (long long)gridDim.x * blockDim.x;
    for (; i < E; i += stride) {
        long long s = load_src(ei, is32, E, i);
        long long t = load_dst(ei, is32, E, i);
        const float2* yr = (const float2*)(y + s * OUT_CH);
        float2 v0 = yr[0], v1 = yr[1], v2 = yr[2], v3 = yr[3], v4 = yr[4];
        float* orow = out + t * OUT_CH;
        atomicAdd(&orow[0], v0.x);
        atomicAdd(&orow[1], v0.y);
        atomicAdd(&orow[2], v1.x);
        atomicAdd(&orow[3], v1.y);
        atomicAdd(&orow[4], v2.x);
        atomicAdd(&orow[5], v2.y);
        atomicAdd(&orow[6], v3.x);
        atomicAdd(&orow[7], v3.y);
        atomicAdd(&orow[8], v4.x);
        atomicAdd(&orow[9], v4.y);
    }
}

__global__ void k_final_fb(const float* __restrict__ dinv,
                           const float* __restrict__ b,
                           float* __restrict__ out, int N) {
    int n = blockIdx.x * blockDim.x + threadIdx.x;
    if (n >= N) return;
    float d = dinv[n];
    float2* orow = (float2*)(out + (size_t)n * OUT_CH);
#pragma unroll
    for (int c2 = 0; c2 < OUT_CH / 2; ++c2) {
        float2 v = orow[c2];
        v.x = v.x * d + b[2 * c2];
        v.y = v.y * d + b[2 * c2 + 1];
        orow[c2] = v;
    }
}

// ============================================================================
// Launch
// ============================================================================

extern "C" void kernel_launch(void* const* d_in, const int* in_sizes, int n_in,
                              void* d_out, int out_size, void* d_ws,
                              size_t ws_size, hipStream_t stream) {
    const float* x = (const float*)d_in[0];
    const void* ei = d_in[1];
    const float* W = (const float*)d_in[2];
    const float* b = (const float*)d_in[3];
    float* out = (float*)d_out;

    int N = in_sizes[0] / IN_CH;  // 100000
    int E = in_sizes[1] / 2;      // 3200000

    int NB = (N + NPB - 1) >> SHIFT;  // buckets (98)
    int nblkN = (N + 255) / 256;
    int nblkC = (E + CHUNK_C - 1) / CHUNK_C;
    int nblkF = (E + CHUNK_F - 1) / CHUNK_F;

    // primary ws layout (4B units):
    //   bcnt[128] | bbase[128] | gcur[128] | flag | pad16 | pdeg[NB*8*1024] |
    //   dinv[N] | pad16 | yw[8N] (32B bf16 rows) | pairs[E] | pad16 |
    //   part[(NB<<sl)*10240]
    size_t off_pdeg = ((size_t)(3 * 128 + 1) + 15) & ~(size_t)15;
    size_t off_dinv = off_pdeg + (size_t)NB * DSPL * NPB;
    size_t off_yw = ((off_dinv + (size_t)N) + 15) & ~(size_t)15;
    size_t off_pairs = off_yw + (size_t)8 * N;
    size_t off_part = ((off_pairs + (size_t)E) + 15) & ~(size_t)15;

    // adaptive split: largest of {16,8,4,2,1} whose partial buffer fits
    int split_log = -1;
    for (int sl = 4; sl >= 0; --sl) {
        size_t needed = (off_part + ((size_t)NB << sl) * (NPB * OUT_CH)) * 4;
        if (ws_size >= needed) {
            split_log = sl;
            break;
        }
    }
    if (split_log > 3) split_log = 3;  // 784 blocks x 8 waves is sufficient

    if (split_log >= 0 && NB <= 128 && N <= (1 << 22)) {
        int* wsi = (int*)d_ws;
        int* bcnt = wsi;
        int* bbase = bcnt + 128;
        int* gcur = bbase + 128;
        int* flag = gcur + 128;
        int* pdeg = wsi + off_pdeg;
        float* dinv = (float*)(wsi + off_dinv);
        unsigned* yw = (unsigned*)(wsi + off_yw);
        int* pairs = wsi + off_pairs;
        float* part = (float*)(wsi + off_part);

        k_init<<<1, 256, 0, stream>>>((const unsigned int*)ei, bcnt, flag, NB,
                                      8192);
        k_bincount<<<nblkC, 256, 0, stream>>>(ei, flag, E, bcnt, NB);
        k_scanNB<<<1, 128, 0, stream>>>(bcnt, bbase, gcur, NB);
        k_binfill<<<nblkF, 256, 0, stream>>>(ei, flag, E, gcur, pairs, NB);
        k_deg_part<<<NB * DSPL, 256, 0, stream>>>(pairs, bbase, bcnt, pdeg);
        k_xw<<<nblkN, 256, 0, stream>>>(x, W, pdeg, dinv, yw, N);
        k_accum<<<NB << split_log, 512, 0, stream>>>(pairs, bbase, bcnt, yw,
                                                     part, split_log);
        int mthreads = N * OUT_CH;
        k_merge<<<(mthreads + 255) / 256, 256, 0, stream>>>(part, yw, dinv, b,
                                                            out, N, split_log);
    } else {
        // -------- fallback: atomic scatter --------
        int* wsi = (int*)d_ws;
        int* cnt = wsi;                     // N
        int* flag = cnt + N;                // 1
        size_t off = ((size_t)N + 2) & ~(size_t)1;
        float* dinv = (float*)(wsi + off);  // N
        float* y = dinv + N;                // 10N

        k_zero_i<<<nblkN, 256, 0, stream>>>(cnt, N);
        k_detect_fb<<<1, 256, 0, stream>>>((const unsigned int*)ei, flag,
                                           8192);
        k_count_fb<<<4096, 256, 0, stream>>>(ei, cnt, flag, E);
        k_xw_fb<<<nblkN, 256, 0, stream>>>(x, W, cnt, dinv, y, out, N);
        k_scatter_fb<<<4096, 256, 0, stream>>>(ei, y, out, flag, E);
        k_final_fb<<<nblkN, 256, 0, stream>>>(dinv, b, out, N);
    }
}